// Round 5
// baseline (6644.958 us; speedup 1.0000x reference)
//
#include <hip/hip_runtime.h>
#include <hip/hip_bf16.h>

typedef __hip_bfloat16 bf16;
typedef unsigned short ushort_t;
typedef unsigned int uint_t;

#define N_USER 200000
#define N_ITEM 100000
#define NEDGE  1000000
#define HID    64

// ---------------------------------------------------------------------------
// dtype helpers. Inputs detected fp32 (R3/R4-verified); bf16 path kept for
// robustness. Intermediates (h, ea_perm) are ALWAYS bf16 (our choice).
// ---------------------------------------------------------------------------
__device__ __forceinline__ float bf2f(uint_t u) {
    uint_t x = u << 16;
    float f; __builtin_memcpy(&f, &x, 4); return f;
}
__device__ __forceinline__ ushort_t f2bf(float f) {
    bf16 h = (bf16)f;
    ushort_t u; __builtin_memcpy(&u, &h, 2); return u;
}
__device__ __forceinline__ float ldf(const void* p, long i, int isf32) {
    if (isf32) return ((const float*)p)[i];
    return bf2f(((const ushort_t*)p)[i]);
}
__device__ __forceinline__ void stf(void* p, long i, int isf32, float v) {
    if (isf32) ((float*)p)[i] = v;
    else       ((ushort_t*)p)[i] = f2bf(v);
}

// fp32-vs-bf16 detector, one wave: fp32 data's interleaved mantissa halves hit
// biased exp >= 137 w.p. ~0.46/word; bf16 N(0,1) never does. 256 words checked.
__global__ void detect_kernel(const ushort_t* __restrict__ x, int* __restrict__ flag) {
    int t = threadIdx.x;   // 64
    int f = 0;
#pragma unroll
    for (int k = 0; k < 4; k++) {
        int ex = (x[t * 4 + k] >> 7) & 0xFF;
        f |= (ex >= 137);
    }
    unsigned long long b = __ballot(f);
    if (t == 0) *flag = (b != 0ULL) ? 1 : 0;
}

// ---------------------------------------------------------------------------
// CSR build: fused dual histogram -> decoupled 3-kernel scan -> fused dual
// scatter that also permutes edge_attr into CSR order as bf16 (eap).
// ---------------------------------------------------------------------------
__global__ __launch_bounds__(256) void hist_kernel(
    const int* __restrict__ src, const int* __restrict__ dst,
    int* __restrict__ cnt_i, int* __restrict__ cnt_u, int E)
{
    int e = blockIdx.x * 256 + threadIdx.x;
    if (e < E) {
        atomicAdd(&cnt_i[dst[e]], 1);
        atomicAdd(&cnt_u[src[e]], 1);
    }
}

// per-block local exclusive scan (8192 elems/block) + block total
__global__ __launch_bounds__(1024) void scan_block_kernel(
    const int* __restrict__ deg, int* __restrict__ local,
    int* __restrict__ partials, int N)
{
    __shared__ int ssum[1024];
    int b = blockIdx.x, tid = threadIdx.x;
    int i0 = b * 8192 + tid * 8;
    int v[8]; int tot = 0;
#pragma unroll
    for (int k = 0; k < 8; k++) { int i = i0 + k; v[k] = (i < N) ? deg[i] : 0; tot += v[k]; }
    ssum[tid] = tot;
    __syncthreads();
    for (int off = 1; off < 1024; off <<= 1) {
        int t = (tid >= off) ? ssum[tid - off] : 0;
        __syncthreads();
        ssum[tid] += t;
        __syncthreads();
    }
    int exc = ssum[tid] - tot;
#pragma unroll
    for (int k = 0; k < 8; k++) { int i = i0 + k; if (i < N) local[i] = exc; exc += v[k]; }
    if (tid == 1023) partials[b] = ssum[1023];
}

__global__ void scan_partials_kernel(int* __restrict__ partials,
                                     int* __restrict__ rowptrN, int nb)
{
    if (threadIdx.x == 0 && blockIdx.x == 0) {
        int a = 0;
        for (int i = 0; i < nb; i++) { int t = partials[i]; partials[i] = a; a += t; }
        *rowptrN = a;
    }
}

__global__ __launch_bounds__(1024) void scan_add_kernel(
    const int* __restrict__ partials, int* __restrict__ rowptr,
    int* __restrict__ cursor, int N)
{
    int b = blockIdx.x, tid = threadIdx.x;
    int i0 = b * 8192 + tid * 8;
    int p = partials[b];
#pragma unroll
    for (int k = 0; k < 8; k++) {
        int i = i0 + k;
        if (i < N) { int v = rowptr[i] + p; rowptr[i] = v; cursor[i] = v; }
    }
}

__global__ __launch_bounds__(256) void scatter_kernel(
    const int* __restrict__ src, const int* __restrict__ dst,
    const void* __restrict__ ea,
    int* __restrict__ cur_i, int* __restrict__ cur_u,
    int* __restrict__ perm_i, int* __restrict__ perm_u,
    ushort_t* __restrict__ eap_i, ushort_t* __restrict__ eap_u,
    int E, const int* __restrict__ flagp)
{
    int e = blockIdx.x * 256 + threadIdx.x;
    if (e >= E) return;
    int isf32 = *flagp;
    uint4 r0, r1;
    if (isf32) {
        const float4* p = (const float4*)((const float*)ea + (long)e * 16);
        float4 f0 = p[0], f1 = p[1], f2 = p[2], f3 = p[3];
        ushort_t h[16];
        h[0]=f2bf(f0.x); h[1]=f2bf(f0.y); h[2]=f2bf(f0.z); h[3]=f2bf(f0.w);
        h[4]=f2bf(f1.x); h[5]=f2bf(f1.y); h[6]=f2bf(f1.z); h[7]=f2bf(f1.w);
        h[8]=f2bf(f2.x); h[9]=f2bf(f2.y); h[10]=f2bf(f2.z); h[11]=f2bf(f2.w);
        h[12]=f2bf(f3.x); h[13]=f2bf(f3.y); h[14]=f2bf(f3.z); h[15]=f2bf(f3.w);
        __builtin_memcpy(&r0, h, 16);
        __builtin_memcpy(&r1, h + 8, 16);
    } else {
        const uint4* p = (const uint4*)((const ushort_t*)ea + (long)e * 16);
        r0 = p[0]; r1 = p[1];
    }
    int s = src[e], d = dst[e];
    int pi = atomicAdd(&cur_i[d], 1);
    perm_i[pi] = s;
    uint4* qi = (uint4*)(eap_i + (long)pi * 16);
    qi[0] = r0; qi[1] = r1;
    int pu = atomicAdd(&cur_u[s], 1);
    perm_u[pu] = d;
    uint4* qu = (uint4*)(eap_u + (long)pu * 16);
    qu[0] = r0; qu[1] = r1;
}

// ---------------------------------------------------------------------------
// Input projection (grid-stride): out[n,c] = relu(x[n,:]@W[:,c] + b[c]),
// bf16 out. Block = 4 rows x 64 cols; W fp32 in LDS staged once per block.
// ---------------------------------------------------------------------------
template<int K>
__global__ __launch_bounds__(256) void proj_kernel(
    const void* __restrict__ x, const void* __restrict__ W,
    const void* __restrict__ b, ushort_t* __restrict__ out, int N,
    const int* __restrict__ flagp)
{
    __shared__ float Ws[K * 64];
    __shared__ float xs[4][K];
    int isf32 = *flagp;
    int tid = threadIdx.x;
    for (int i = tid; i < K * 64; i += 256) Ws[i] = ldf(W, i, isf32);
    int r = tid >> 6, c = tid & 63;
    float bc = ldf(b, c, isf32);
    for (int row0 = blockIdx.x * 4; row0 < N; row0 += gridDim.x * 4) {
        __syncthreads();   // WAR on xs (and Ws staging, first iter)
        for (int i = tid; i < 4 * K; i += 256) {
            int rr = i / K, k = i - rr * K;
            int row = row0 + rr;
            xs[rr][k] = (row < N) ? ldf(x, (long)row * K + k, isf32) : 0.f;
        }
        __syncthreads();
        int row = row0 + r;
        float acc = bc;
#pragma unroll
        for (int k = 0; k < K; k++) acc = fmaf(xs[r][k], Ws[k * 64 + c], acc);
        if (row < N) out[(long)row * 64 + c] = f2bf(fmaxf(acc, 0.f));
    }
}

// one edge's ea@We contribution for lane-column c (row = 16 bf16 in 2 uint4)
__device__ __forceinline__ float row_fma(uint4 A, uint4 B,
                                         const float* __restrict__ Wes,
                                         int c, float m)
{
    uint_t u;
    u = A.x; m = fmaf(bf2f(u & 0xffff), Wes[0*64+c], m);  m = fmaf(bf2f(u >> 16), Wes[1*64+c], m);
    u = A.y; m = fmaf(bf2f(u & 0xffff), Wes[2*64+c], m);  m = fmaf(bf2f(u >> 16), Wes[3*64+c], m);
    u = A.z; m = fmaf(bf2f(u & 0xffff), Wes[4*64+c], m);  m = fmaf(bf2f(u >> 16), Wes[5*64+c], m);
    u = A.w; m = fmaf(bf2f(u & 0xffff), Wes[6*64+c], m);  m = fmaf(bf2f(u >> 16), Wes[7*64+c], m);
    u = B.x; m = fmaf(bf2f(u & 0xffff), Wes[8*64+c], m);  m = fmaf(bf2f(u >> 16), Wes[9*64+c], m);
    u = B.y; m = fmaf(bf2f(u & 0xffff), Wes[10*64+c], m); m = fmaf(bf2f(u >> 16), Wes[11*64+c], m);
    u = B.z; m = fmaf(bf2f(u & 0xffff), Wes[12*64+c], m); m = fmaf(bf2f(u >> 16), Wes[13*64+c], m);
    u = B.w; m = fmaf(bf2f(u & 0xffff), Wes[14*64+c], m); m = fmaf(bf2f(u >> 16), Wes[15*64+c], m);
    return m;
}

// ---------------------------------------------------------------------------
// Fused GINE conv, one wave per dst node, NO barriers in the node loop:
//   acc[c] = sum_j relu(h_src[perm_j][c] + eap[j]@We[:,c] + be[c])
//   o = relu(relu(((1+eps)h+acc)@W1+b1)@W2+b2) (+h if RESID)
// MLP k-sums via __shfl (wave-private), weights fp32 in LDS (36.75 KB ->
// 4 blocks/CU x 8 waves = 32 waves/CU at VGPR<=64). h and eap are bf16.
// ---------------------------------------------------------------------------
template<int RESID>
__global__ __launch_bounds__(512, 8) void conv_kernel(
    const ushort_t* __restrict__ h_src, const ushort_t* __restrict__ h_dst,
    const int* __restrict__ rowptr, const int* __restrict__ perm,
    const ushort_t* __restrict__ eap,
    const void* __restrict__ We, const void* __restrict__ be,
    const void* __restrict__ W1, const void* __restrict__ b1,
    const void* __restrict__ W2, const void* __restrict__ b2,
    const void* __restrict__ eps, int conv,
    ushort_t* __restrict__ outh, void* __restrict__ outv, long outoff,
    int N, const int* __restrict__ flagp)
{
    __shared__ float Wes[16 * 64];
    __shared__ float W1s[64 * 64];
    __shared__ float W2s[64 * 64];
    __shared__ float bes[64], b1s[64], b2s[64];
    int isf32 = *flagp;
    int tid = threadIdx.x;
    long woff = (long)conv * 4096, weoff = (long)conv * 1024, boff = (long)conv * 64;
    for (int i = tid; i < 4096; i += 512) {
        W1s[i] = ldf(W1, woff + i, isf32);
        W2s[i] = ldf(W2, woff + i, isf32);
    }
    for (int i = tid; i < 1024; i += 512) Wes[i] = ldf(We, weoff + i, isf32);
    if (tid < 64) {
        bes[tid] = ldf(be, boff + tid, isf32);
        b1s[tid] = ldf(b1, boff + tid, isf32);
        b2s[tid] = ldf(b2, boff + tid, isf32);
    }
    __syncthreads();   // weight staging only — no barriers after this
    float eps1 = 1.f + ldf(eps, conv, isf32);
    int c = tid & 63;
    int wave = blockIdx.x * 8 + (tid >> 6);
    int nwaves = gridDim.x * 8;

    for (int n = wave; n < N; n += nwaves) {
        float hv = bf2f(h_dst[(long)n * 64 + c]);
        int jb = rowptr[n], je = rowptr[n + 1];
        float acc = 0.f;
        float bec = bes[c];
        int j = jb;
        for (; j + 4 <= je; j += 4) {
            int s0 = perm[j], s1 = perm[j + 1], s2 = perm[j + 2], s3 = perm[j + 3];
            float h0 = bf2f(h_src[(long)s0 * 64 + c]);
            float h1 = bf2f(h_src[(long)s1 * 64 + c]);
            float h2 = bf2f(h_src[(long)s2 * 64 + c]);
            float h3 = bf2f(h_src[(long)s3 * 64 + c]);
            const uint4* q = (const uint4*)(eap + (long)j * 16);
            uint4 A, B;
            float m0 = bec, m1 = bec, m2 = bec, m3 = bec;
            A = q[0]; B = q[1]; m0 = row_fma(A, B, Wes, c, m0);
            A = q[2]; B = q[3]; m1 = row_fma(A, B, Wes, c, m1);
            A = q[4]; B = q[5]; m2 = row_fma(A, B, Wes, c, m2);
            A = q[6]; B = q[7]; m3 = row_fma(A, B, Wes, c, m3);
            acc += fmaxf(m0 + h0, 0.f) + fmaxf(m1 + h1, 0.f)
                 + fmaxf(m2 + h2, 0.f) + fmaxf(m3 + h3, 0.f);
        }
        for (; j < je; j++) {
            int s0 = perm[j];
            float h0 = bf2f(h_src[(long)s0 * 64 + c]);
            const uint4* q = (const uint4*)(eap + (long)j * 16);
            uint4 A = q[0], B = q[1];
            float m0 = row_fma(A, B, Wes, c, bec);
            acc += fmaxf(m0 + h0, 0.f);
        }
        float v = eps1 * hv + acc;
        float t = b1s[c];
#pragma unroll
        for (int k = 0; k < 64; k++) t = fmaf(__shfl(v, k, 64), W1s[k * 64 + c], t);
        t = fmaxf(t, 0.f);
        float o = b2s[c];
#pragma unroll
        for (int k = 0; k < 64; k++) o = fmaf(__shfl(t, k, 64), W2s[k * 64 + c], o);
        o = fmaxf(o, 0.f);
        if (RESID) o += hv;
        long base = (long)n * 64 + c;
        if (outh) outh[base] = f2bf(o);
        else      stf(outv, outoff + base, isf32, o);
    }
}

extern "C" void kernel_launch(void* const* d_in, const int* in_sizes, int n_in,
                              void* d_out, int out_size, void* d_ws, size_t ws_size,
                              hipStream_t stream)
{
    const void* x_user    = d_in[0];
    const void* x_item    = d_in[1];
    const void* edge_attr = d_in[2];
    const int*  src_idx   = (const int*)d_in[3];
    const int*  dst_idx   = (const int*)d_in[4];
    const void* Wp_user   = d_in[5];
    const void* bp_user   = d_in[6];
    const void* Wp_item   = d_in[7];
    const void* bp_item   = d_in[8];
    const void* eps       = d_in[9];
    const void* We        = d_in[10];
    const void* be        = d_in[11];
    const void* W1        = d_in[12];
    const void* b1        = d_in[13];
    const void* W2        = d_in[14];
    const void* b2        = d_in[15];

    // Workspace (~151.3 MB), all 256B-aligned offsets.
    char* W = (char*)d_ws;
    int*      flag     = (int*)W;                                   // @0 (1 KB)
    ushort_t* h_u      = (ushort_t*)(W + 1024);                     // 25.6 MB
    ushort_t* h_i      = (ushort_t*)(W + 25601024);                 // 12.8 MB
    ushort_t* h_u2     = (ushort_t*)(W + 38401024);                 // 25.6 MB
    ushort_t* h_i2     = (ushort_t*)(W + 64001024);                 // 12.8 MB
    int*      rowptr_i = (int*)(W + 76801024);                      // 100001 (pad)
    int*      rowptr_u = (int*)(W + 77201408);                      // 200001 (pad)
    int*      cursor_i = (int*)(W + 78001664);                      // 100000
    int*      cursor_u = (int*)(W + 78401664);                      // 200000 (contiguous w/ cursor_i)
    int*      perm_i   = (int*)(W + 79201664);                      // 1M
    int*      perm_u   = (int*)(W + 83201664);                      // 1M
    ushort_t* eap_i    = (ushort_t*)(W + 87201664);                 // 32 MB
    ushort_t* eap_u    = (ushort_t*)(W + 119201664);                // 32 MB
    int*      part_i   = (int*)(W + 151201664);                     // 64
    int*      part_u   = (int*)(W + 151201920);                     // 64

    const int EG   = (NEDGE + 255) / 256;
    const int NB_I = (N_ITEM + 8191) / 8192;   // 13
    const int NB_U = (N_USER + 8191) / 8192;   // 25

    detect_kernel<<<1, 64, 0, stream>>>((const ushort_t*)x_user, flag);

    // CSR build (both directions)
    hipMemsetAsync(cursor_i, 0, (size_t)(N_ITEM + N_USER) * sizeof(int), stream);
    hist_kernel<<<EG, 256, 0, stream>>>(src_idx, dst_idx, cursor_i, cursor_u, NEDGE);
    scan_block_kernel<<<NB_I, 1024, 0, stream>>>(cursor_i, rowptr_i, part_i, N_ITEM);
    scan_partials_kernel<<<1, 64, 0, stream>>>(part_i, rowptr_i + N_ITEM, NB_I);
    scan_add_kernel<<<NB_I, 1024, 0, stream>>>(part_i, rowptr_i, cursor_i, N_ITEM);
    scan_block_kernel<<<NB_U, 1024, 0, stream>>>(cursor_u, rowptr_u, part_u, N_USER);
    scan_partials_kernel<<<1, 64, 0, stream>>>(part_u, rowptr_u + N_USER, NB_U);
    scan_add_kernel<<<NB_U, 1024, 0, stream>>>(part_u, rowptr_u, cursor_u, N_USER);
    scatter_kernel<<<EG, 256, 0, stream>>>(src_idx, dst_idx, edge_attr,
                                           cursor_i, cursor_u, perm_i, perm_u,
                                           eap_i, eap_u, NEDGE, flag);

    // input projections (bf16 h out)
    proj_kernel<128><<<1024, 256, 0, stream>>>(x_user, Wp_user, bp_user, h_u, N_USER, flag);
    proj_kernel<64><<<1024, 256, 0, stream>>>(x_item, Wp_item, bp_item, h_i, N_ITEM, flag);

    // layer 0: (h_u,h_i) -> (h_u2,h_i2), bf16, no residual
    conv_kernel<0><<<1024, 512, 0, stream>>>(h_u, h_i, rowptr_i, perm_i, eap_i,
        We, be, W1, b1, W2, b2, eps, 0, h_i2, nullptr, 0, N_ITEM, flag);
    conv_kernel<0><<<1024, 512, 0, stream>>>(h_i, h_u, rowptr_u, perm_u, eap_u,
        We, be, W1, b1, W2, b2, eps, 1, h_u2, nullptr, 0, N_USER, flag);

    // layer 1: (h_u2,h_i2) -> d_out (flagged dtype), residual
    conv_kernel<1><<<1024, 512, 0, stream>>>(h_u2, h_i2, rowptr_i, perm_i, eap_i,
        We, be, W1, b1, W2, b2, eps, 2, nullptr, d_out, (long)N_USER * HID, N_ITEM, flag);
    conv_kernel<1><<<1024, 512, 0, stream>>>(h_i2, h_u2, rowptr_u, perm_u, eap_u,
        We, be, W1, b1, W2, b2, eps, 3, nullptr, d_out, 0, N_USER, flag);
}